// Round 21
// baseline (1545.877 us; speedup 1.0000x reference)
//
#include <hip/hip_runtime.h>
#include <hip/hip_bf16.h>

typedef __attribute__((ext_vector_type(8))) short bf16x8;
typedef __attribute__((ext_vector_type(4))) float f32x4;
typedef unsigned short u16;
typedef unsigned int u32;

#define DT_ (10.0f / 9.0f)

__device__ __forceinline__ u16 f2bf(float f) {
  u32 u = __float_as_uint(f);
  u = (u + 0x7FFFu + ((u >> 16) & 1u)) >> 16;
  return (u16)u;
}

// Packed RNE f32x2 -> bf16x2 (one v_cvt_pk_bf16_f32).
__device__ __forceinline__ u32 cvtpk(float lo, float hi) {
  __hip_bfloat162 h = __float22bfloat162_rn(float2{lo, hi});
  return *reinterpret_cast<u32*>(&h);
}

__device__ __forceinline__ float tanh_fast(float x) {
  float ax = fabsf(x);
  float e = __expf(-2.0f * ax);
  float t = (1.0f - e) * __builtin_amdgcn_rcpf(1.0f + e);
  return copysignf(t, x);
}

// Fragment read from LDS: row-major [rows][K], row stride strideB bytes,
// XOR-swizzled with ((row&7)<<4).
__device__ __forceinline__ bf16x8 frag_lds(const u16* Mb, int row0, int kE, int strideB) {
  const int l = threadIdx.x & 63;
  const int r = row0 + (l & 15);
  const int kb = (kE + ((l >> 4) << 3)) << 1;
  const int off = r * strideB + (kb ^ ((r & 7) << 4));
  return *(const bf16x8*)((const char*)Mb + off);
}

// Fragment straight from global row-major [rows][K] (weights, L2-resident).
__device__ __forceinline__ bf16x8 frag_glb(const u16* WT, int row0, int kE, int K) {
  const int l = threadIdx.x & 63;
  const int j = row0 + (l & 15);
  const int k = kE + ((l >> 4) << 3);
  return *(const bf16x8*)(WT + j * K + k);
}

// gemm2 (A-stages, s5): MT=4,NT=2; 2-deep pipeline; outer loop unroll-1
// (R11: full unroll hoists loads and spills past the 128-VGPR grant).
template <int KST, bool BLDS>
__device__ __forceinline__ void gemm2(f32x4 (&acc)[4][2], const u16* Ab, int aStrideB, int mb,
                                      const u16* Bp, int bK, int nb) {
#pragma unroll
  for (int mt = 0; mt < 4; ++mt)
#pragma unroll
    for (int nt = 0; nt < 2; ++nt) acc[mt][nt] = (f32x4){0.f, 0.f, 0.f, 0.f};
  bf16x8 av0[4], bv0[2], av1[4], bv1[2];
#pragma unroll
  for (int nt = 0; nt < 2; ++nt) {
    if constexpr (BLDS) bv0[nt] = frag_lds(Bp, nb + nt * 16, 0, 256);
    else                bv0[nt] = frag_glb(Bp, nb + nt * 16, 0, bK);
  }
#pragma unroll
  for (int mt = 0; mt < 4; ++mt) av0[mt] = frag_lds(Ab, mb + mt * 16, 0, aStrideB);
#pragma unroll 1
  for (int ks = 0; ks < KST; ks += 2) {
    const int k1 = (ks + 1) * 32;
#pragma unroll
    for (int nt = 0; nt < 2; ++nt) {
      if constexpr (BLDS) bv1[nt] = frag_lds(Bp, nb + nt * 16, k1, 256);
      else                bv1[nt] = frag_glb(Bp, nb + nt * 16, k1, bK);
    }
#pragma unroll
    for (int mt = 0; mt < 4; ++mt) av1[mt] = frag_lds(Ab, mb + mt * 16, k1, aStrideB);
#pragma unroll
    for (int nt = 0; nt < 2; ++nt)
#pragma unroll
      for (int mt = 0; mt < 4; ++mt)
        acc[mt][nt] = __builtin_amdgcn_mfma_f32_16x16x32_bf16(av0[mt], bv0[nt], acc[mt][nt], 0, 0, 0);
    if (ks + 2 < KST) {
      const int k2 = (ks + 2) * 32;
#pragma unroll
      for (int nt = 0; nt < 2; ++nt) {
        if constexpr (BLDS) bv0[nt] = frag_lds(Bp, nb + nt * 16, k2, 256);
        else                bv0[nt] = frag_glb(Bp, nb + nt * 16, k2, bK);
      }
#pragma unroll
      for (int mt = 0; mt < 4; ++mt) av0[mt] = frag_lds(Ab, mb + mt * 16, k2, aStrideB);
    }
#pragma unroll
    for (int nt = 0; nt < 2; ++nt)
#pragma unroll
      for (int mt = 0; mt < 4; ++mt)
        acc[mt][nt] = __builtin_amdgcn_mfma_f32_16x16x32_bf16(av1[mt], bv1[nt], acc[mt][nt], 0, 0, 0);
  }
}

// gemmW (big W-stages s2/s3): MT=2, NT=8 — 10 LDS/global reads per 16 MFMA vs 12/16
// for two NT=2 passes. 1-deep (acc 64 + frags 40 must stay under the 128-VGPR grant;
// R15 showed 2-deep is neutral anyway). A from LDS, B = weights from global (L2).
template <int KST>
__device__ __forceinline__ void gemmW(f32x4 (&acc)[2][8], const u16* Ab, int aStrideB, int mb,
                                      const u16* WT, int bK, int nb) {
#pragma unroll
  for (int mt = 0; mt < 2; ++mt)
#pragma unroll
    for (int nt = 0; nt < 8; ++nt) acc[mt][nt] = (f32x4){0.f, 0.f, 0.f, 0.f};
#pragma unroll 1
  for (int ks = 0; ks < KST; ++ks) {
    const int kE = ks * 32;
    bf16x8 bv[8];
#pragma unroll
    for (int nt = 0; nt < 8; ++nt) bv[nt] = frag_glb(WT, nb + nt * 16, kE, bK);
    bf16x8 av[2];
#pragma unroll
    for (int mt = 0; mt < 2; ++mt) av[mt] = frag_lds(Ab, mb + mt * 16, kE, aStrideB);
#pragma unroll
    for (int nt = 0; nt < 8; ++nt)
#pragma unroll
      for (int mt = 0; mt < 2; ++mt)
        acc[mt][nt] = __builtin_amdgcn_mfma_f32_16x16x32_bf16(av[mt], bv[nt], acc[mt][nt], 0, 0, 0);
  }
}

// Single-column-block pass (stage 6), 2-deep pipeline.
template <int KST>
__device__ __forceinline__ void gemm1(f32x4 (&acc)[4], const u16* Ab, int mb,
                                      const u16* Bp, int nb) {
#pragma unroll
  for (int mt = 0; mt < 4; ++mt) acc[mt] = (f32x4){0.f, 0.f, 0.f, 0.f};
  bf16x8 av0[4], av1[4];
  bf16x8 bv0, bv1;
  bv0 = frag_lds(Bp, nb, 0, 256);
#pragma unroll
  for (int mt = 0; mt < 4; ++mt) av0[mt] = frag_lds(Ab, mb + mt * 16, 0, 256);
#pragma unroll 1
  for (int ks = 0; ks < KST; ks += 2) {
    const int k1 = (ks + 1) * 32;
    bv1 = frag_lds(Bp, nb, k1, 256);
#pragma unroll
    for (int mt = 0; mt < 4; ++mt) av1[mt] = frag_lds(Ab, mb + mt * 16, k1, 256);
#pragma unroll
    for (int mt = 0; mt < 4; ++mt)
      acc[mt] = __builtin_amdgcn_mfma_f32_16x16x32_bf16(av0[mt], bv0, acc[mt], 0, 0, 0);
    if (ks + 2 < KST) {
      const int k2 = (ks + 2) * 32;
      bv0 = frag_lds(Bp, nb, k2, 256);
#pragma unroll
      for (int mt = 0; mt < 4; ++mt) av0[mt] = frag_lds(Ab, mb + mt * 16, k2, 256);
    }
#pragma unroll
    for (int mt = 0; mt < 4; ++mt)
      acc[mt] = __builtin_amdgcn_mfma_f32_16x16x32_bf16(av1[mt], bv1, acc[mt], 0, 0, 0);
  }
}

// uint2 feat-major epilogue (stride 256B), MT=4/NT=2 (A-stages, s5).
__device__ __forceinline__ void epi_T2(const f32x4 (&acc)[4][2], u16* Q, int nb, int mb, int lane) {
  const int l15 = lane & 15, lg = lane >> 4;
#pragma unroll
  for (int nt = 0; nt < 2; ++nt) {
    const int c = nb + nt * 16 + l15;
    const int swz = (c & 7) << 4;
    char* rowp = (char*)Q + c * 256;
#pragma unroll
    for (int mt = 0; mt < 4; ++mt) {
      f32x4 v = acc[mt][nt];
      const int r0 = mb + mt * 16 + (lg << 2);
      uint2 pk;
      pk.x = cvtpk(v.x, v.y);
      pk.y = cvtpk(v.z, v.w);
      *(uint2*)(rowp + ((r0 << 1) ^ swz)) = pk;
    }
  }
}

// uint2 feat-major epilogue for gemmW output (MT=2, NT=8): t2 -> Q, stride 256B.
__device__ __forceinline__ void epi_TW(const f32x4 (&acc)[2][8], u16* Q, int nb, int mb, int lane) {
  const int l15 = lane & 15, lg = lane >> 4;
#pragma unroll
  for (int nt = 0; nt < 8; ++nt) {
    const int c = nb + nt * 16 + l15;
    const int swz = (c & 7) << 4;
    char* rowp = (char*)Q + c * 256;
#pragma unroll
    for (int mt = 0; mt < 2; ++mt) {
      f32x4 v = acc[mt][nt];
      const int r0 = mb + mt * 16 + (lg << 2);
      uint2 pk;
      pk.x = cvtpk(v.x, v.y);
      pk.y = cvtpk(v.z, v.w);
      *(uint2*)(rowp + ((r0 << 1) ^ swz)) = pk;
    }
  }
}

// Node-major scalar epilogue (no bias): Az -> [node][inf], stride 256B (s1, MT=4/NT=2).
__device__ __forceinline__ void epi_N2(const f32x4 (&acc)[4][2], u16* Dst, int nb, int mb, int lane) {
  const int l15 = lane & 15, lg = lane >> 4;
#pragma unroll
  for (int nt = 0; nt < 2; ++nt) {
    const int c = nb + nt * 16 + l15;
    const int csh = c << 1;
#pragma unroll
    for (int mt = 0; mt < 4; ++mt) {
      f32x4 v = acc[mt][nt];
      const int r0 = mb + mt * 16 + (lg << 2);
      const u32 p01 = cvtpk(v.x, v.y);
      const u32 p23 = cvtpk(v.z, v.w);
      *(u16*)((char*)Dst + (r0 + 0) * 256 + (csh ^ (((r0 + 0) & 7) << 4))) = (u16)p01;
      *(u16*)((char*)Dst + (r0 + 1) * 256 + (csh ^ (((r0 + 1) & 7) << 4))) = (u16)(p01 >> 16);
      *(u16*)((char*)Dst + (r0 + 2) * 256 + (csh ^ (((r0 + 2) & 7) << 4))) = (u16)p23;
      *(u16*)((char*)Dst + (r0 + 3) * 256 + (csh ^ (((r0 + 3) & 7) << 4))) = (u16)(p23 >> 16);
    }
  }
}

// Node-major scalar epilogue + bias(col)+tanh, MT=4/NT=2 (s4): h -> P stride 512B.
__device__ __forceinline__ void epi_H2(const f32x4 (&acc)[4][2], u16* P, const float* __restrict__ b,
                                       int nb, int mb, int lane) {
  const int l15 = lane & 15, lg = lane >> 4;
#pragma unroll
  for (int nt = 0; nt < 2; ++nt) {
    const int c = nb + nt * 16 + l15;
    const float bb = b[c];
    const int csh = c << 1;
#pragma unroll
    for (int mt = 0; mt < 4; ++mt) {
      f32x4 v = acc[mt][nt];
      const int r0 = mb + mt * 16 + (lg << 2);
      float t0 = tanh_fast(v.x + bb), t1 = tanh_fast(v.y + bb);
      float t2 = tanh_fast(v.z + bb), t3 = tanh_fast(v.w + bb);
      const u32 p01 = cvtpk(t0, t1);
      const u32 p23 = cvtpk(t2, t3);
      *(u16*)((char*)P + (r0 + 0) * 512 + (csh ^ (((r0 + 0) & 7) << 4))) = (u16)p01;
      *(u16*)((char*)P + (r0 + 1) * 512 + (csh ^ (((r0 + 1) & 7) << 4))) = (u16)(p01 >> 16);
      *(u16*)((char*)P + (r0 + 2) * 512 + (csh ^ (((r0 + 2) & 7) << 4))) = (u16)p23;
      *(u16*)((char*)P + (r0 + 3) * 512 + (csh ^ (((r0 + 3) & 7) << 4))) = (u16)(p23 >> 16);
    }
  }
}

// Node-major scalar epilogue + bias(col)+tanh for gemmW (MT=2, NT=8): h1 -> P, 512B.
__device__ __forceinline__ void epi_HW(const f32x4 (&acc)[2][8], u16* P, const float* __restrict__ b,
                                       int nb, int mb, int lane) {
  const int l15 = lane & 15, lg = lane >> 4;
#pragma unroll
  for (int nt = 0; nt < 8; ++nt) {
    const int c = nb + nt * 16 + l15;
    const float bb = b[c];
    const int csh = c << 1;
#pragma unroll
    for (int mt = 0; mt < 2; ++mt) {
      f32x4 v = acc[mt][nt];
      const int r0 = mb + mt * 16 + (lg << 2);
      float t0 = tanh_fast(v.x + bb), t1 = tanh_fast(v.y + bb);
      float t2 = tanh_fast(v.z + bb), t3 = tanh_fast(v.w + bb);
      const u32 p01 = cvtpk(t0, t1);
      const u32 p23 = cvtpk(t2, t3);
      *(u16*)((char*)P + (r0 + 0) * 512 + (csh ^ (((r0 + 0) & 7) << 4))) = (u16)p01;
      *(u16*)((char*)P + (r0 + 1) * 512 + (csh ^ (((r0 + 1) & 7) << 4))) = (u16)(p01 >> 16);
      *(u16*)((char*)P + (r0 + 2) * 512 + (csh ^ (((r0 + 2) & 7) << 4))) = (u16)p23;
      *(u16*)((char*)P + (r0 + 3) * 512 + (csh ^ (((r0 + 3) & 7) << 4))) = (u16)(p23 >> 16);
    }
  }
}

// One f(z) evaluation (R18 structure; s2/s3 retiled MT=2/NT=8):
//  s1: Az = A@z (all-LDS)      -> Q-lo node-major          [2m x 4n]
//  s2: h1 = tanh(Az@W1+b1)     -> P node-major (512B)      [4m x 2n, NT=8]
//  s3: t2 = h1@W2              -> Q feat-major             [4m x 2n, NT=8]
//  s4: h2 = tanh(A@t2+b2)      -> P node-major             [2m x 4n]
//  s5: t3 = h2@W3              -> Q-lo feat-major          [2m x 4n]
//  s6: k = A@t3 + RK epilogue  -> z^T Q-hi; state in ws slabs SA/SB.
template <int E>
__device__ __forceinline__ void feval(int step,
    u16* P, u16* Q, const u16* As,
    const u16* __restrict__ W1T, const u16* __restrict__ W2T, const u16* __restrict__ W3T,
    const float* __restrict__ b1, const float* __restrict__ b2, const float* __restrict__ b3,
    f32x4* __restrict__ SA, f32x4* __restrict__ SB,
    float* __restrict__ out,
    int batch, int tid, int lane, int mb, int wn) {
  const int l15 = lane & 15, lg = lane >> 4;
  const int wid = tid >> 6;
  const int mbW = (wid >> 1) * 32;   // W-stage M base (4-way m split)
  const int cbW = (wid & 1) * 128;   // W-stage N base (2-way n split)
  u16* Qhi = Q + 16384;  // z^T region (32 KB)

  { // s1: Az = A @ z  [M128 N128 K128]; A=As, B=z^T (Qhi)
    f32x4 acc[4][2];
    gemm2<4, true>(acc, As, 256, mb, Qhi, 0, wn * 32);
    epi_N2(acc, Q, wn * 32, mb, lane);
  }
  __syncthreads();
  { // s2: h1 = tanh(Az @ W1 + b1) [M128 N256 K128]; A=Az (Q-lo), B=W1T global
    f32x4 acc[2][8];
    gemmW<4>(acc, Q, 256, mbW, W1T, 128, cbW);
    epi_HW(acc, P, b1, cbW, mbW, lane);
  }
  __syncthreads();
  { // s3: t2 = h1 @ W2 [M128 N256 K256]; A=h1 (P,512B), B=W2T global
    f32x4 acc[2][8];
    gemmW<8>(acc, P, 512, mbW, W2T, 256, cbW);
    epi_TW(acc, Q, cbW, mbW, lane);
  }
  __syncthreads();
  // s4: h2 = tanh(A @ t2 + b2) [M128 N256 K128]; A=As, B=t2 (Q)
#pragma unroll 1
  for (int h = 0; h < 2; ++h) {
    f32x4 acc[4][2];
    gemm2<4, true>(acc, As, 256, mb, Q, 0, h * 128 + wn * 32);
    epi_H2(acc, P, b2, h * 128 + wn * 32, mb, lane);
  }
  __syncthreads();
  { // s5: t3 = h2 @ W3 [M128 N128 K256]; A=h2 (P,512B), B=W3T global
    f32x4 acc[4][2];
    gemm2<8, false>(acc, P, 512, mb, W3T, 256, wn * 32);
    epi_T2(acc, Q, wn * 32, mb, lane);
  }
  __syncthreads();

  // s6: k = A @ t3 + b3 [M128 N128 K128] + fused RK epilogue; z^T -> Q-hi (uint2)
#pragma unroll 1
  for (int p = 0; p < 2; ++p) {
    f32x4 ya[4], ba[4];
#pragma unroll
    for (int q = 0; q < 4; ++q) ya[q] = SA[(p * 4 + q) * 512 + tid];
    if constexpr (E == 2 || E == 3) {
#pragma unroll
      for (int q = 0; q < 4; ++q) ba[q] = SB[(p * 4 + q) * 512 + tid];
    }
    f32x4 acc[4];
    gemm1<4>(acc, As, mb, Q, wn * 32 + p * 16);
    const int c = wn * 32 + p * 16 + l15;
    const float bb = b3[c];
    const int swz = (c & 7) << 4;
    char* zrow = (char*)Qhi + c * 256;
#pragma unroll
    for (int mt = 0; mt < 4; ++mt) {
      f32x4 v = acc[mt];
      const int r0 = mb + mt * 16 + (lg << 2);
      const int i4 = p * 4 + mt;
      f32x4 wa, wb, zv;
#pragma unroll
      for (int e = 0; e < 4; ++e) {
        const int r = r0 + e;
        const float kv = v[e] + bb;
        float z;
        if constexpr (E == 1) {
          wb[e] = kv;                                   // k1 -> SB
          z = ya[mt][e] + (DT_ * (1.0f / 3.0f)) * kv;
        } else if constexpr (E == 2) {
          const float k1 = ba[mt][e];
          const float y = ya[mt][e];
          z = y + DT_ * (kv - k1 * (1.0f / 3.0f));
          wb[e] = y + DT_ * (k1 - kv);                  // U -> SB
          wa[e] = y + (DT_ * 0.125f) * (k1 + 3.0f * kv);  // V -> SA
        } else if constexpr (E == 3) {
          z = ba[mt][e] + DT_ * kv;                     // z4 = U + dt*k3
          wa[e] = ya[mt][e] + (DT_ * 0.375f) * kv;      // W -> SA
        } else {
          const float yn = ya[mt][e] + (DT_ * 0.125f) * kv;
          wa[e] = yn;                                   // yn -> SA
          __builtin_nontemporal_store(yn, &out[batch * 163840 + r * 1280 + (step + 1) * 128 + c]);
          z = yn;
        }
        zv[e] = z;
      }
      uint2 pk;
      pk.x = cvtpk(zv.x, zv.y);
      pk.y = cvtpk(zv.z, zv.w);
      *(uint2*)(zrow + ((r0 << 1) ^ swz)) = pk;         // z^T feat-major
      if constexpr (E == 1 || E == 2) SB[i4 * 512 + tid] = wb;
      if constexpr (E != 1) SA[i4 * 512 + tid] = wa;
    }
  }
  __syncthreads();
}

__global__ __launch_bounds__(512, 2)  // 8-wave block, 1 block/CU -> 2 waves/EU
void ode_main(
    const u16* __restrict__ Aswz,
    const u16* __restrict__ W1T, const u16* __restrict__ W2T, const u16* __restrict__ W3T,
    const float* __restrict__ b1, const float* __restrict__ b2, const float* __restrict__ b3,
    const float* __restrict__ x,
    f32x4* __restrict__ KS,
    float* __restrict__ out) {
  __shared__ u16 P[32768];   // 64 KB: h1/h2 node-major (stride 512)
  __shared__ u16 Q[32768];   // 64 KB: lo = Az/t3, full = t2; hi = z^T
  __shared__ u16 As[16384];  // 32 KB: normalized adjacency, pre-swizzled
  const int tid = threadIdx.x;
  const int lane = tid & 63;
  const int wid = tid >> 6;
  const int wm = wid >> 2, wn = wid & 3;
  const int mb = wm * 64;
  const int l15 = lane & 15, lg = lane >> 4;
  const int batch = blockIdx.x;
  f32x4* SA = KS + batch * 8192;       // 64 KB slab: y / V / W / yn
  f32x4* SB = SA + 4096;               // 64 KB slab: k1 / U
  u16* Qhi = Q + 16384;

  { // stage adjacency into LDS (pre-swizzled in ws -> linear copy); 2048 uint4
    const uint4* s = (const uint4*)Aswz;
    uint4* d = (uint4*)As;
#pragma unroll
    for (int i = 0; i < 4; ++i) d[tid + i * 512] = s[tid + i * 512];
  }

  // init: y0 -> SA slab; seed z^T into Q-hi (uint2); write out step-0 slot.
#pragma unroll 1
  for (int p = 0; p < 2; ++p)
#pragma unroll 1
    for (int mt = 0; mt < 4; ++mt) {
      const int c = wn * 32 + p * 16 + l15;
      const int r0 = mb + mt * 16 + (lg << 2);
      f32x4 w;
#pragma unroll
      for (int e = 0; e < 4; ++e) {
        const int r = r0 + e;
        const float v = x[((batch * 128 + r) * 12 + 11) * 128 + c];
        w[e] = v;
        __builtin_nontemporal_store(v, &out[batch * 163840 + r * 1280 + c]);
      }
      uint2 pk;
      pk.x = cvtpk(w.x, w.y);
      pk.y = cvtpk(w.z, w.w);
      *(uint2*)((char*)Qhi + c * 256 + ((r0 << 1) ^ ((c & 7) << 4))) = pk;
      SA[(p * 4 + mt) * 512 + tid] = w;
    }
  __syncthreads();

  for (int s = 0; s < 9; ++s) {
    feval<1>(s, P, Q, As, W1T, W2T, W3T, b1, b2, b3, SA, SB, out, batch, tid, lane, mb, wn);
    feval<2>(s, P, Q, As, W1T, W2T, W3T, b1, b2, b3, SA, SB, out, batch, tid, lane, mb, wn);
    feval<3>(s, P, Q, As, W1T, W2T, W3T, b1, b2, b3, SA, SB, out, batch, tid, lane, mb, wn);
    feval<4>(s, P, Q, As, W1T, W2T, W3T, b1, b2, b3, SA, SB, out, batch, tid, lane, mb, wn);
  }
}

// ---- prep kernels ----

__global__ void prep_adj_k(const float* __restrict__ adjw, u16* __restrict__ Aswz) {
  const int n = blockIdx.x;
  const int m = threadIdx.x;  // 128 threads = 2 waves
  const float w = adjw[n * 128 + m];
  const float sg = 1.0f / (1.0f + __expf(-w));
  float s = sg;
#pragma unroll
  for (int o = 1; o < 64; o <<= 1) s += __shfl_xor(s, o);
  __shared__ float red[2];
  if ((m & 63) == 0) red[m >> 6] = s;
  __syncthreads();
  const float deg = fmaxf(red[0] + red[1], 1.0f);
  const float v = sg / deg;
  *(u16*)((char*)Aswz + n * 256 + ((m << 1) ^ ((n & 7) << 4))) = f2bf(v);
}

__global__ void prep_w_k(const float* __restrict__ W1, const float* __restrict__ W2,
                         const float* __restrict__ W3,
                         u16* __restrict__ W1T, u16* __restrict__ W2T, u16* __restrict__ W3T) {
  const int i = blockIdx.x * 256 + threadIdx.x;
  if (i < 32768) {
    W1T[i] = f2bf(W1[(i & 127) * 256 + (i >> 7)]);  // W1T[hid][f] = W1[f][hid]
    W3T[i] = f2bf(W3[(i & 255) * 128 + (i >> 8)]);  // W3T[f][hid] = W3[hid][f]
  }
  if (i < 65536) W2T[i] = f2bf(W2[(i & 255) * 256 + (i >> 8)]);  // W2T[h2][h1] = W2[h1][h2]
}

extern "C" void kernel_launch(void* const* d_in, const int* in_sizes, int n_in,
                              void* d_out, int out_size, void* d_ws, size_t ws_size,
                              hipStream_t stream) {
  const float* x    = (const float*)d_in[0];
  const float* adjw = (const float*)d_in[1];
  const float* W1   = (const float*)d_in[2];
  const float* b1   = (const float*)d_in[3];
  const float* W2   = (const float*)d_in[4];
  const float* b2   = (const float*)d_in[5];
  const float* W3   = (const float*)d_in[6];
  const float* b3   = (const float*)d_in[7];
  float* out = (float*)d_out;

  u16* Aswz = (u16*)d_ws;
  u16* W1T = Aswz + 16384;
  u16* W2T = W1T + 32768;
  u16* W3T = W2T + 65536;
  f32x4* KS = (f32x4*)(W3T + 32768);  // 128 blocks x 128 KB = 16 MB RK state slabs

  prep_adj_k<<<128, 128, 0, stream>>>(adjw, Aswz);
  prep_w_k<<<256, 256, 0, stream>>>(W1, W2, W3, W1T, W2T, W3T);
  ode_main<<<128, 512, 0, stream>>>(Aswz, W1T, W2T, W3T, b1, b2, b3, x, KS, out);
}

// Round 22
// 915.134 us; speedup vs baseline: 1.6892x; 1.6892x over previous
//
#include <hip/hip_runtime.h>
#include <hip/hip_bf16.h>

typedef __attribute__((ext_vector_type(8))) short bf16x8;
typedef __attribute__((ext_vector_type(4))) float f32x4;
typedef unsigned short u16;
typedef unsigned int u32;

#define DT_ (10.0f / 9.0f)

__device__ __forceinline__ u16 f2bf(float f) {
  u32 u = __float_as_uint(f);
  u = (u + 0x7FFFu + ((u >> 16) & 1u)) >> 16;
  return (u16)u;
}

// Packed RNE f32x2 -> bf16x2 (one v_cvt_pk_bf16_f32).
__device__ __forceinline__ u32 cvtpk(float lo, float hi) {
  __hip_bfloat162 h = __float22bfloat162_rn(float2{lo, hi});
  return *reinterpret_cast<u32*>(&h);
}

__device__ __forceinline__ float tanh_fast(float x) {
  float ax = fabsf(x);
  float e = __expf(-2.0f * ax);
  float t = (1.0f - e) * __builtin_amdgcn_rcpf(1.0f + e);
  return copysignf(t, x);
}

// Fragment read from LDS: row-major [rows][K], row stride strideB bytes,
// XOR-swizzled with ((row&7)<<4).
__device__ __forceinline__ bf16x8 frag_lds(const u16* Mb, int row0, int kE, int strideB) {
  const int l = threadIdx.x & 63;
  const int r = row0 + (l & 15);
  const int kb = (kE + ((l >> 4) << 3)) << 1;
  const int off = r * strideB + (kb ^ ((r & 7) << 4));
  return *(const bf16x8*)((const char*)Mb + off);
}

// Fragment straight from global row-major [rows][K] (weights, L2-resident).
__device__ __forceinline__ bf16x8 frag_glb(const u16* WT, int row0, int kE, int K) {
  const int l = threadIdx.x & 63;
  const int j = row0 + (l & 15);
  const int k = kE + ((l >> 4) << 3);
  return *(const bf16x8*)(WT + j * K + k);
}

// gemm2: MT=4,NT=2; 2-deep pipeline; outer loop unroll-1
// (R11: full unroll hoists loads and spills past the 128-VGPR grant).
template <int KST, bool BLDS>
__device__ __forceinline__ void gemm2(f32x4 (&acc)[4][2], const u16* Ab, int aStrideB, int mb,
                                      const u16* Bp, int bK, int nb) {
#pragma unroll
  for (int mt = 0; mt < 4; ++mt)
#pragma unroll
    for (int nt = 0; nt < 2; ++nt) acc[mt][nt] = (f32x4){0.f, 0.f, 0.f, 0.f};
  bf16x8 av0[4], bv0[2], av1[4], bv1[2];
#pragma unroll
  for (int nt = 0; nt < 2; ++nt) {
    if constexpr (BLDS) bv0[nt] = frag_lds(Bp, nb + nt * 16, 0, 256);
    else                bv0[nt] = frag_glb(Bp, nb + nt * 16, 0, bK);
  }
#pragma unroll
  for (int mt = 0; mt < 4; ++mt) av0[mt] = frag_lds(Ab, mb + mt * 16, 0, aStrideB);
#pragma unroll 1
  for (int ks = 0; ks < KST; ks += 2) {
    const int k1 = (ks + 1) * 32;
#pragma unroll
    for (int nt = 0; nt < 2; ++nt) {
      if constexpr (BLDS) bv1[nt] = frag_lds(Bp, nb + nt * 16, k1, 256);
      else                bv1[nt] = frag_glb(Bp, nb + nt * 16, k1, bK);
    }
#pragma unroll
    for (int mt = 0; mt < 4; ++mt) av1[mt] = frag_lds(Ab, mb + mt * 16, k1, aStrideB);
#pragma unroll
    for (int nt = 0; nt < 2; ++nt)
#pragma unroll
      for (int mt = 0; mt < 4; ++mt)
        acc[mt][nt] = __builtin_amdgcn_mfma_f32_16x16x32_bf16(av0[mt], bv0[nt], acc[mt][nt], 0, 0, 0);
    if (ks + 2 < KST) {
      const int k2 = (ks + 2) * 32;
#pragma unroll
      for (int nt = 0; nt < 2; ++nt) {
        if constexpr (BLDS) bv0[nt] = frag_lds(Bp, nb + nt * 16, k2, 256);
        else                bv0[nt] = frag_glb(Bp, nb + nt * 16, k2, bK);
      }
#pragma unroll
      for (int mt = 0; mt < 4; ++mt) av0[mt] = frag_lds(Ab, mb + mt * 16, k2, aStrideB);
    }
#pragma unroll
    for (int nt = 0; nt < 2; ++nt)
#pragma unroll
      for (int mt = 0; mt < 4; ++mt)
        acc[mt][nt] = __builtin_amdgcn_mfma_f32_16x16x32_bf16(av1[mt], bv1[nt], acc[mt][nt], 0, 0, 0);
  }
}

// Single-column-block pass (stage 6), 2-deep pipeline.
template <int KST>
__device__ __forceinline__ void gemm1(f32x4 (&acc)[4], const u16* Ab, int mb,
                                      const u16* Bp, int nb) {
#pragma unroll
  for (int mt = 0; mt < 4; ++mt) acc[mt] = (f32x4){0.f, 0.f, 0.f, 0.f};
  bf16x8 av0[4], av1[4];
  bf16x8 bv0, bv1;
  bv0 = frag_lds(Bp, nb, 0, 256);
#pragma unroll
  for (int mt = 0; mt < 4; ++mt) av0[mt] = frag_lds(Ab, mb + mt * 16, 0, 256);
#pragma unroll 1
  for (int ks = 0; ks < KST; ks += 2) {
    const int k1 = (ks + 1) * 32;
    bv1 = frag_lds(Bp, nb, k1, 256);
#pragma unroll
    for (int mt = 0; mt < 4; ++mt) av1[mt] = frag_lds(Ab, mb + mt * 16, k1, 256);
#pragma unroll
    for (int mt = 0; mt < 4; ++mt)
      acc[mt] = __builtin_amdgcn_mfma_f32_16x16x32_bf16(av0[mt], bv0, acc[mt], 0, 0, 0);
    if (ks + 2 < KST) {
      const int k2 = (ks + 2) * 32;
      bv0 = frag_lds(Bp, nb, k2, 256);
#pragma unroll
      for (int mt = 0; mt < 4; ++mt) av0[mt] = frag_lds(Ab, mb + mt * 16, k2, 256);
    }
#pragma unroll
    for (int mt = 0; mt < 4; ++mt)
      acc[mt] = __builtin_amdgcn_mfma_f32_16x16x32_bf16(av1[mt], bv1, acc[mt], 0, 0, 0);
  }
}

// uint2 epilogue: D[M,N] -> storage [N][M-contig], row stride SB, swizzle key N&7.
template <int SB>
__device__ __forceinline__ void epi_U2(const f32x4 (&acc)[4][2], u16* Dst, int nb, int mb, int lane) {
  const int l15 = lane & 15, lg = lane >> 4;
#pragma unroll
  for (int nt = 0; nt < 2; ++nt) {
    const int c = nb + nt * 16 + l15;
    const int swz = (c & 7) << 4;
    char* rowp = (char*)Dst + c * SB;
#pragma unroll
    for (int mt = 0; mt < 4; ++mt) {
      f32x4 v = acc[mt][nt];
      const int r0 = mb + mt * 16 + (lg << 2);
      uint2 pk;
      pk.x = cvtpk(v.x, v.y);
      pk.y = cvtpk(v.z, v.w);
      *(uint2*)(rowp + ((r0 << 1) ^ swz)) = pk;
    }
  }
}

// uint2 epilogue with bias (along M rows) + tanh.
template <int SB>
__device__ __forceinline__ void epi_U2H(const f32x4 (&acc)[4][2], u16* Dst,
                                        const float* __restrict__ b, int nb, int mb, int lane) {
  const int l15 = lane & 15, lg = lane >> 4;
#pragma unroll
  for (int nt = 0; nt < 2; ++nt) {
    const int c = nb + nt * 16 + l15;
    const int swz = (c & 7) << 4;
    char* rowp = (char*)Dst + c * SB;
#pragma unroll
    for (int mt = 0; mt < 4; ++mt) {
      f32x4 v = acc[mt][nt];
      const int r0 = mb + mt * 16 + (lg << 2);
      const f32x4 bb = *(const f32x4*)(b + r0);
      float t0 = tanh_fast(v.x + bb.x), t1 = tanh_fast(v.y + bb.y);
      float t2 = tanh_fast(v.z + bb.z), t3 = tanh_fast(v.w + bb.w);
      uint2 pk;
      pk.x = cvtpk(t0, t1);
      pk.y = cvtpk(t2, t3);
      *(uint2*)(rowp + ((r0 << 1) ^ swz)) = pk;
    }
  }
}

// Feat-major uint2 epilogue (t^T), stride 256B (s3/s5 outputs).
__device__ __forceinline__ void epi_T2(const f32x4 (&acc)[4][2], u16* Q, int nb, int mb, int lane) {
  const int l15 = lane & 15, lg = lane >> 4;
#pragma unroll
  for (int nt = 0; nt < 2; ++nt) {
    const int c = nb + nt * 16 + l15;
    const int swz = (c & 7) << 4;
    char* rowp = (char*)Q + c * 256;
#pragma unroll
    for (int mt = 0; mt < 4; ++mt) {
      f32x4 v = acc[mt][nt];
      const int r0 = mb + mt * 16 + (lg << 2);
      uint2 pk;
      pk.x = cvtpk(v.x, v.y);
      pk.y = cvtpk(v.z, v.w);
      *(uint2*)(rowp + ((r0 << 1) ^ swz)) = pk;
    }
  }
}

// Node-major scalar epilogue + bias(col)+tanh (s2: h1 -> P, 512B).
__device__ __forceinline__ void epi_H2(const f32x4 (&acc)[4][2], u16* P, const float* __restrict__ b,
                                       int nb, int mb, int lane) {
  const int l15 = lane & 15, lg = lane >> 4;
#pragma unroll
  for (int nt = 0; nt < 2; ++nt) {
    const int c = nb + nt * 16 + l15;
    const float bb = b[c];
    const int csh = c << 1;
#pragma unroll
    for (int mt = 0; mt < 4; ++mt) {
      f32x4 v = acc[mt][nt];
      const int r0 = mb + mt * 16 + (lg << 2);
      float t0 = tanh_fast(v.x + bb), t1 = tanh_fast(v.y + bb);
      float t2 = tanh_fast(v.z + bb), t3 = tanh_fast(v.w + bb);
      const u32 p01 = cvtpk(t0, t1);
      const u32 p23 = cvtpk(t2, t3);
      *(u16*)((char*)P + (r0 + 0) * 512 + (csh ^ (((r0 + 0) & 7) << 4))) = (u16)p01;
      *(u16*)((char*)P + (r0 + 1) * 512 + (csh ^ (((r0 + 1) & 7) << 4))) = (u16)(p01 >> 16);
      *(u16*)((char*)P + (r0 + 2) * 512 + (csh ^ (((r0 + 2) & 7) << 4))) = (u16)p23;
      *(u16*)((char*)P + (r0 + 3) * 512 + (csh ^ (((r0 + 3) & 7) << 4))) = (u16)(p23 >> 16);
    }
  }
}

// One f(z) evaluation (R18 structure; s1/s4 swapped to all-LDS transposed forms
// with uint2 epilogues — the proven-safe half of R19):
//  s1: (Az)^T-form (A=z^T, B=As)        -> Az node-major, uint2   (Q-lo, 256B)
//  s2: h1 = tanh(Az@W1+b1)              -> P node-major, scalar   (B=W1T global)
//  s3: t2 = h1@W2                       -> Q feat-major, uint2    (B=W2T global)
//  s4: h2^T-form (A=t2^T, B=As) + tanh  -> h2 node-major, uint2   (P, 512B)
//  s5: t3 = h2@W3                       -> Q-lo feat-major, uint2 (B=W3T global)
//  s6: k = A@t3 + RK epilogue           -> z^T Q-hi; state in ws slabs SA/SB.
template <int E>
__device__ __forceinline__ void feval(int step,
    u16* P, u16* Q, const u16* As,
    const u16* __restrict__ W1T, const u16* __restrict__ W2T, const u16* __restrict__ W3T,
    const float* __restrict__ b1, const float* __restrict__ b2, const float* __restrict__ b3,
    f32x4* __restrict__ SA, f32x4* __restrict__ SB,
    float* __restrict__ out,
    int batch, int tid, int lane, int mb, int wn) {
  const int l15 = lane & 15, lg = lane >> 4;
  u16* Qhi = Q + 16384;  // z^T region (32 KB)

  { // s1: M=feat128, N=node128, K=node128. A = z^T (Qhi, 256B), B = As. ALL-LDS.
    f32x4 acc[4][2];
    gemm2<4, true>(acc, Qhi, 256, mb, As, 0, wn * 32);
    epi_U2<256>(acc, Q, wn * 32, mb, lane);   // Az node-major [node][inf]
  }
  __syncthreads();
  // s2: h1 = tanh(Az @ W1 + b1) [M128 N256 K128]; A=Az (Q-lo), B=W1T global
#pragma unroll 1
  for (int h = 0; h < 2; ++h) {
    f32x4 acc[4][2];
    gemm2<4, false>(acc, Q, 256, mb, W1T, 128, h * 128 + wn * 32);
    epi_H2(acc, P, b1, h * 128 + wn * 32, mb, lane);
  }
  __syncthreads();
  // s3: t2 = h1 @ W2 [M128 N256 K256]; A=h1 (P,512B), B=W2T global
#pragma unroll 1
  for (int h = 0; h < 2; ++h) {
    f32x4 acc[4][2];
    gemm2<8, false>(acc, P, 512, mb, W2T, 256, h * 128 + wn * 32);
    epi_T2(acc, Q, h * 128 + wn * 32, mb, lane);
  }
  __syncthreads();
  // s4: M=feat256 (2 passes), N=node128, K=node128. A = t2^T (Q, 256B), B = As. ALL-LDS.
#pragma unroll 1
  for (int h = 0; h < 2; ++h) {
    f32x4 acc[4][2];
    gemm2<4, true>(acc, Q, 256, h * 128 + mb, As, 0, wn * 32);
    epi_U2H<512>(acc, P, b2, wn * 32, h * 128 + mb, lane);  // h2 node-major
  }
  __syncthreads();
  { // s5: t3 = h2 @ W3 [M128 N128 K256]; A=h2 (P,512B), B=W3T global
    f32x4 acc[4][2];
    gemm2<8, false>(acc, P, 512, mb, W3T, 256, wn * 32);
    epi_T2(acc, Q, wn * 32, mb, lane);
  }
  __syncthreads();

  // s6: k = A @ t3 + b3 [M128 N128 K128] + fused RK epilogue; z^T -> Q-hi (uint2)
#pragma unroll 1
  for (int p = 0; p < 2; ++p) {
    f32x4 ya[4], ba[4];
#pragma unroll
    for (int q = 0; q < 4; ++q) ya[q] = SA[(p * 4 + q) * 512 + tid];
    if constexpr (E == 2 || E == 3) {
#pragma unroll
      for (int q = 0; q < 4; ++q) ba[q] = SB[(p * 4 + q) * 512 + tid];
    }
    f32x4 acc[4];
    gemm1<4>(acc, As, mb, Q, wn * 32 + p * 16);
    const int c = wn * 32 + p * 16 + l15;
    const float bb = b3[c];
    const int swz = (c & 7) << 4;
    char* zrow = (char*)Qhi + c * 256;
#pragma unroll
    for (int mt = 0; mt < 4; ++mt) {
      f32x4 v = acc[mt];
      const int r0 = mb + mt * 16 + (lg << 2);
      const int i4 = p * 4 + mt;
      f32x4 wa, wb, zv;
#pragma unroll
      for (int e = 0; e < 4; ++e) {
        const int r = r0 + e;
        const float kv = v[e] + bb;
        float z;
        if constexpr (E == 1) {
          wb[e] = kv;                                   // k1 -> SB
          z = ya[mt][e] + (DT_ * (1.0f / 3.0f)) * kv;
        } else if constexpr (E == 2) {
          const float k1 = ba[mt][e];
          const float y = ya[mt][e];
          z = y + DT_ * (kv - k1 * (1.0f / 3.0f));
          wb[e] = y + DT_ * (k1 - kv);                  // U -> SB
          wa[e] = y + (DT_ * 0.125f) * (k1 + 3.0f * kv);  // V -> SA
        } else if constexpr (E == 3) {
          z = ba[mt][e] + DT_ * kv;                     // z4 = U + dt*k3
          wa[e] = ya[mt][e] + (DT_ * 0.375f) * kv;      // W -> SA
        } else {
          const float yn = ya[mt][e] + (DT_ * 0.125f) * kv;
          wa[e] = yn;                                   // yn -> SA
          __builtin_nontemporal_store(yn, &out[batch * 163840 + r * 1280 + (step + 1) * 128 + c]);
          z = yn;
        }
        zv[e] = z;
      }
      uint2 pk;
      pk.x = cvtpk(zv.x, zv.y);
      pk.y = cvtpk(zv.z, zv.w);
      *(uint2*)(zrow + ((r0 << 1) ^ swz)) = pk;         // z^T feat-major
      if constexpr (E == 1 || E == 2) SB[i4 * 512 + tid] = wb;
      if constexpr (E != 1) SA[i4 * 512 + tid] = wa;
    }
  }
  __syncthreads();
}

__global__ __launch_bounds__(512, 2)  // 8-wave block, 1 block/CU -> 2 waves/EU
void ode_main(
    const u16* __restrict__ Aswz,
    const u16* __restrict__ W1T, const u16* __restrict__ W2T, const u16* __restrict__ W3T,
    const float* __restrict__ b1, const float* __restrict__ b2, const float* __restrict__ b3,
    const float* __restrict__ x,
    f32x4* __restrict__ KS,
    float* __restrict__ out) {
  __shared__ u16 P[32768];   // 64 KB: h1/h2 node-major (stride 512)
  __shared__ u16 Q[32768];   // 64 KB: lo = Az/t3, full = t2; hi = z^T
  __shared__ u16 As[16384];  // 32 KB: normalized adjacency, pre-swizzled
  const int tid = threadIdx.x;
  const int lane = tid & 63;
  const int wid = tid >> 6;
  const int wm = wid >> 2, wn = wid & 3;
  const int mb = wm * 64;
  const int l15 = lane & 15, lg = lane >> 4;
  const int batch = blockIdx.x;
  f32x4* SA = KS + batch * 8192;       // 64 KB slab: y / V / W / yn
  f32x4* SB = SA + 4096;               // 64 KB slab: k1 / U
  u16* Qhi = Q + 16384;

  { // stage adjacency into LDS (pre-swizzled in ws -> linear copy); 2048 uint4
    const uint4* s = (const uint4*)Aswz;
    uint4* d = (uint4*)As;
#pragma unroll
    for (int i = 0; i < 4; ++i) d[tid + i * 512] = s[tid + i * 512];
  }

  // init: y0 -> SA slab; seed z^T into Q-hi (uint2); write out step-0 slot.
#pragma unroll 1
  for (int p = 0; p < 2; ++p)
#pragma unroll 1
    for (int mt = 0; mt < 4; ++mt) {
      const int c = wn * 32 + p * 16 + l15;
      const int r0 = mb + mt * 16 + (lg << 2);
      f32x4 w;
#pragma unroll
      for (int e = 0; e < 4; ++e) {
        const int r = r0 + e;
        const float v = x[((batch * 128 + r) * 12 + 11) * 128 + c];
        w[e] = v;
        __builtin_nontemporal_store(v, &out[batch * 163840 + r * 1280 + c]);
      }
      uint2 pk;
      pk.x = cvtpk(w.x, w.y);
      pk.y = cvtpk(w.z, w.w);
      *(uint2*)((char*)Qhi + c * 256 + ((r0 << 1) ^ ((c & 7) << 4))) = pk;
      SA[(p * 4 + mt) * 512 + tid] = w;
    }
  __syncthreads();

  for (int s = 0; s < 9; ++s) {
    feval<1>(s, P, Q, As, W1T, W2T, W3T, b1, b2, b3, SA, SB, out, batch, tid, lane, mb, wn);
    feval<2>(s, P, Q, As, W1T, W2T, W3T, b1, b2, b3, SA, SB, out, batch, tid, lane, mb, wn);
    feval<3>(s, P, Q, As, W1T, W2T, W3T, b1, b2, b3, SA, SB, out, batch, tid, lane, mb, wn);
    feval<4>(s, P, Q, As, W1T, W2T, W3T, b1, b2, b3, SA, SB, out, batch, tid, lane, mb, wn);
  }
}

// ---- prep kernels ----

__global__ void prep_adj_k(const float* __restrict__ adjw, u16* __restrict__ Aswz) {
  const int n = blockIdx.x;
  const int m = threadIdx.x;  // 128 threads = 2 waves
  const float w = adjw[n * 128 + m];
  const float sg = 1.0f / (1.0f + __expf(-w));
  float s = sg;
#pragma unroll
  for (int o = 1; o < 64; o <<= 1) s += __shfl_xor(s, o);
  __shared__ float red[2];
  if ((m & 63) == 0) red[m >> 6] = s;
  __syncthreads();
  const float deg = fmaxf(red[0] + red[1], 1.0f);
  const float v = sg / deg;
  *(u16*)((char*)Aswz + n * 256 + ((m << 1) ^ ((n & 7) << 4))) = f2bf(v);
}

__global__ void prep_w_k(const float* __restrict__ W1, const float* __restrict__ W2,
                         const float* __restrict__ W3,
                         u16* __restrict__ W1T, u16* __restrict__ W2T, u16* __restrict__ W3T) {
  const int i = blockIdx.x * 256 + threadIdx.x;
  if (i < 32768) {
    W1T[i] = f2bf(W1[(i & 127) * 256 + (i >> 7)]);  // W1T[hid][f] = W1[f][hid]
    W3T[i] = f2bf(W3[(i & 255) * 128 + (i >> 8)]);  // W3T[f][hid] = W3[hid][f]
  }
  if (i < 65536) W2T[i] = f2bf(W2[(i & 255) * 256 + (i >> 8)]);  // W2T[h2][h1] = W2[h1][h2]
}

extern "C" void kernel_launch(void* const* d_in, const int* in_sizes, int n_in,
                              void* d_out, int out_size, void* d_ws, size_t ws_size,
                              hipStream_t stream) {
  const float* x    = (const float*)d_in[0];
  const float* adjw = (const float*)d_in[1];
  const float* W1   = (const float*)d_in[2];
  const float* b1   = (const float*)d_in[3];
  const float* W2   = (const float*)d_in[4];
  const float* b2   = (const float*)d_in[5];
  const float* W3   = (const float*)d_in[6];
  const float* b3   = (const float*)d_in[7];
  float* out = (float*)d_out;

  u16* Aswz = (u16*)d_ws;
  u16* W1T = Aswz + 16384;
  u16* W2T = W1T + 32768;
  u16* W3T = W2T + 65536;
  f32x4* KS = (f32x4*)(W3T + 32768);  // 128 blocks x 128 KB = 16 MB RK state slabs

  prep_adj_k<<<128, 128, 0, stream>>>(adjw, Aswz);
  prep_w_k<<<256, 256, 0, stream>>>(W1, W2, W3, W1T, W2T, W3T);
  ode_main<<<128, 512, 0, stream>>>(Aswz, W1T, W2T, W3T, b1, b2, b3, x, KS, out);
}